// Round 6
// baseline (143.616 us; speedup 1.0000x reference)
//
#include <hip/hip_runtime.h>

#define IMG 224
#define HW (IMG * IMG)
#define HW4 (HW / 4)
#define NB 128
#define NPTS 16384

// ---------------------------------------------------------------------------
// Kernel 1: one block per batch, 1024 thr, float4 loads. Writes per-batch
// params {zmin, 0.7/(zmax-zmin+1e-6)} to ws.
// ---------------------------------------------------------------------------
__global__ __launch_bounds__(1024) void k_minmax(const float* __restrict__ pts,
                                                 const float* __restrict__ az,
                                                 const float* __restrict__ el,
                                                 float* __restrict__ params) {
    const int b = blockIdx.x;
    const int tid = threadIdx.x;

    float sa, ca, se, ce;
    __sincosf(az[b], &sa, &ca);
    __sincosf(el[b], &se, &ce);
    const float r20 = -ce * sa, r21 = se, r22 = ce * ca;

    const float4* __restrict__ pb4 = (const float4*)(pts + (size_t)b * NPTS * 3);

    float zmin = 1e30f, zmax = -1e30f;
#pragma unroll
    for (int it = 0; it < 4; ++it) {               // 12 independent float4 loads
        const int t = it * 1024 + tid;
        const float4 v0 = pb4[3 * t + 0];
        const float4 v1 = pb4[3 * t + 1];
        const float4 v2 = pb4[3 * t + 2];
        float rz;
        rz = r20 * v0.x + r21 * v0.y + r22 * v0.z; zmin = fminf(zmin, rz); zmax = fmaxf(zmax, rz);
        rz = r20 * v0.w + r21 * v1.x + r22 * v1.y; zmin = fminf(zmin, rz); zmax = fmaxf(zmax, rz);
        rz = r20 * v1.z + r21 * v1.w + r22 * v2.x; zmin = fminf(zmin, rz); zmax = fmaxf(zmax, rz);
        rz = r20 * v2.y + r21 * v2.z + r22 * v2.w; zmin = fminf(zmin, rz); zmax = fmaxf(zmax, rz);
    }

    for (int m = 1; m < 64; m <<= 1) {
        zmin = fminf(zmin, __shfl_xor(zmin, m));
        zmax = fmaxf(zmax, __shfl_xor(zmax, m));
    }
    __shared__ float wmin[16], wmax[16];
    const int wid = tid >> 6;
    if ((tid & 63) == 0) { wmin[wid] = zmin; wmax[wid] = zmax; }
    __syncthreads();
    if (tid == 0) {
#pragma unroll
        for (int w = 1; w < 16; ++w) {
            zmin = fminf(zmin, wmin[w]);
            zmax = fmaxf(zmax, wmax[w]);
        }
        params[2 * b + 0] = zmin;
        params[2 * b + 1] = 0.7f / (zmax - zmin + 1e-6f);
    }
}

// ---------------------------------------------------------------------------
// Kernel 2: splat with async LDS point staging (double-buffered, counted
// vmcnt, raw s_barrier). Grid = NB*4 blocks x 512 thr, 2 blocks/CU.
// Block (b,q) owns rows [q*56, q*56+56); blockIdx = q*128+b keeps all 4
// quarter-blocks of batch b on XCD b%8.
// ---------------------------------------------------------------------------
#define SROWS 56
#define TILEF (SROWS * IMG)          // 12544 floats = 49 KB
#define CH_PTS 1024
#define CH_FLOATS (CH_PTS * 3)       // 3072 floats = 12 KB
#define NCH (NPTS / CH_PTS)          // 16 chunks

__global__ __launch_bounds__(512) void k_splat(const float* __restrict__ pts,
                                               const float* __restrict__ az,
                                               const float* __restrict__ el,
                                               const float* __restrict__ params,
                                               float* __restrict__ out) {
    __shared__ __align__(16) float tile[TILEF];
    __shared__ __align__(16) float buf[2][CH_FLOATS];

    const int b = blockIdx.x & (NB - 1);
    const int q = blockIdx.x >> 7;            // 0..3
    const int y0 = q * SROWS;
    const int tid = threadIdx.x;
    const int w = tid >> 6;                   // wave 0..7
    const int l = tid & 63;

    float sa, ca, se, ce;
    __sincosf(az[b], &sa, &ca);
    __sincosf(el[b], &se, &ce);
    const float r00 = ca,       r02 = sa;
    const float r10 = se * sa,  r11 = ce,  r12 = -se * ca;
    const float r20 = -ce * sa, r21 = se,  r22 = ce * ca;

    const float zmin = params[2 * b + 0];
    const float inv  = params[2 * b + 1];
    // force params materialized (and their waitcnt) before staging begins
    asm volatile("" :: "v"(zmin), "v"(inv));

    // zero the tile
    for (int i = tid; i < TILEF; i += 512) tile[i] = 0.0f;

    const char* gbase = (const char*)(pts + (size_t)b * NPTS * 3);

    // stage chunk c (12288 B = 768 x 16B slots) into buf[bi]:
    // waves 0-7 copy slots 0-511, waves 0-3 additionally copy slots 512-767.
    auto stage = [&](int c, int bi) {
        const char* g = gbase + (size_t)c * 12288;
        char* lb = (char*)buf[bi];
        __builtin_amdgcn_global_load_lds(
            (const __attribute__((address_space(1))) void*)(g + (w * 64 + l) * 16),
            (__attribute__((address_space(3))) void*)(lb + w * 1024), 16, 0, 0);
        if (w < 4) {
            __builtin_amdgcn_global_load_lds(
                (const __attribute__((address_space(1))) void*)(g + 8192 + (w * 64 + l) * 16),
                (__attribute__((address_space(3))) void*)(lb + 8192 + w * 1024), 16, 0, 0);
        }
    };

    auto proc = [&](float x, float y, float z) {
        const float rx = r00 * x + r02 * z;
        const float ry = r10 * x + r11 * y + r12 * z;
        const float rz = r20 * x + r21 * y + r22 * z;
        const float px = (rx + 1.0f) * (0.5f * IMG) - 0.5f;
        const float py = (ry + 1.0f) * (0.5f * IMG) - 0.5f;
        const float fx = floorf(px);
        const float fy = floorf(py);
        if (fx >= 0.0f && fy >= 0.0f && fx < (float)(IMG - 1) && fy < (float)(IMG - 1)) {
            const float feat = 0.3f + (rz - zmin) * inv;
            const float wx2 = px - fx, wx1 = 1.0f - wx2;
            const float wy2 = py - fy, wy1 = 1.0f - wy2;
            const int ix = (int)fx;
            const int r0 = (int)fy - y0;
            const int r1 = r0 + 1;
            if (r0 >= 0 && r0 < SROWS) {
                atomicAdd(&tile[r0 * IMG + ix],     wx1 * wy1 * feat);
                atomicAdd(&tile[r0 * IMG + ix + 1], wx2 * wy1 * feat);
            }
            if (r1 >= 0 && r1 < SROWS) {
                atomicAdd(&tile[r1 * IMG + ix],     wx1 * wy2 * feat);
                atomicAdd(&tile[r1 * IMG + ix + 1], wx2 * wy2 * feat);
            }
        }
    };

    // prologue: 2 chunks in flight
    stage(0, 0);
    stage(1, 1);
    // tile zeros committed before first barrier
    asm volatile("s_waitcnt lgkmcnt(0)" ::: "memory");

    for (int i = 0; i < NCH; ++i) {
        // wait for own slice of chunk i (leave chunk i+1's loads in flight)
        if (i < NCH - 1) {
            if (w < 4) asm volatile("s_waitcnt vmcnt(2)" ::: "memory");
            else       asm volatile("s_waitcnt vmcnt(1)" ::: "memory");
        } else {
            asm volatile("s_waitcnt vmcnt(0)" ::: "memory");
        }
        __builtin_amdgcn_s_barrier();          // all slices of chunk i landed

        const float2* c2 = (const float2*)buf[i & 1];
        const float2 a0 = c2[3 * tid + 0];
        const float2 a1 = c2[3 * tid + 1];
        const float2 a2 = c2[3 * tid + 2];
        proc(a0.x, a0.y, a1.x);                // point 2*tid
        proc(a1.y, a2.x, a2.y);                // point 2*tid+1

        __builtin_amdgcn_s_barrier();          // all reads of buf[i&1] done
        if (i + 2 < NCH) stage(i + 2, i & 1);  // refill the buffer just freed
    }

    // drain own LDS atomics, then sync before reading the tile
    asm volatile("s_waitcnt lgkmcnt(0)" ::: "memory");
    __builtin_amdgcn_s_barrier();

    // writeout: exclusive region -> 3 broadcast channels
    const float4* __restrict__ t4 = (const float4*)tile;
    float4* __restrict__ o4 = (float4*)(out + (size_t)b * 3 * HW + (size_t)y0 * IMG);
    for (int i = tid; i < TILEF / 4; i += 512) {
        const float4 v = t4[i];
        o4[i] = v;
        o4[i + HW4] = v;
        o4[i + 2 * HW4] = v;
    }
}

extern "C" void kernel_launch(void* const* d_in, const int* in_sizes, int n_in,
                              void* d_out, int out_size, void* d_ws, size_t ws_size,
                              hipStream_t stream) {
    const float* pts = (const float*)d_in[0];
    const float* az  = (const float*)d_in[1];
    const float* el  = (const float*)d_in[2];
    float* params = (float*)d_ws;    // 256 floats
    float* out = (float*)d_out;

    k_minmax<<<NB, 1024, 0, stream>>>(pts, az, el, params);
    k_splat<<<NB * 4, 512, 0, stream>>>(pts, az, el, params, out);
}

// Round 8
// 138.593 us; speedup vs baseline: 1.0362x; 1.0362x over previous
//
#include <hip/hip_runtime.h>

#define IMG 224
#define HW (IMG * IMG)
#define HW4 (HW / 4)
#define NB 128
#define NPTS 16384

#define GROUPS 8
#define RPB (IMG / GROUPS)            // 28 rows per block
#define TILEF (RPB * IMG)             // 6272 floats = 25088 B LDS
#define THREADS 512
#define NW (THREADS / 64)             // 8 waves

typedef float vf4 __attribute__((ext_vector_type(4)));

// Single fused kernel. Grid = NB*GROUPS = 1024 blocks x 512 thr.
// Block (b, g) owns image rows [g*28, (g+1)*28) of batch b.
// blockIdx = g*128 + b: all 8 sibling groups of batch b land on XCD b%8 ->
// the batch's 196 KB of points is read 16x (pass1 + pass2, 8 siblings) but
// only ~1x from HBM, rest from that XCD's L2.
// Pass 1: in-block z min/max (wave shuffle + LDS cross-wave reduce).
// Pass 2: transform + bilinear splat into 28x224 LDS tile via ds_add_f32.
// Writeout: exclusive region -> 3 broadcast channels, nontemporal stores.
__global__ __launch_bounds__(THREADS) void k_render(const float* __restrict__ pts,
                                                    const float* __restrict__ az,
                                                    const float* __restrict__ el,
                                                    float* __restrict__ out) {
    __shared__ __align__(16) float tile[TILEF];
    __shared__ float wmin[NW], wmax[NW];

    const int b = blockIdx.x & (NB - 1);
    const int g = blockIdx.x >> 7;        // 0..7
    const int y0 = g * RPB;
    const int tid = threadIdx.x;

    // Rotation matrix R = R_el @ R_az (wave-uniform scalars).
    float sa, ca, se, ce;
    __sincosf(az[b], &sa, &ca);
    __sincosf(el[b], &se, &ce);
    const float r00 = ca,       r02 = sa;
    const float r10 = se * sa,  r11 = ce,  r12 = -se * ca;
    const float r20 = -ce * sa, r21 = se,  r22 = ce * ca;

    const float4* __restrict__ pb4 = (const float4*)(pts + (size_t)b * NPTS * 3);

    // Zero the tile (published by the __syncthreads after pass 1).
    for (int i = tid; i < TILEF; i += THREADS) tile[i] = 0.0f;

    // ---- pass 1: z min/max over all 16K points (3 float4 = 4 pts/iter) ----
    float zmin = 1e30f, zmax = -1e30f;
#pragma unroll
    for (int it = 0; it < NPTS / (4 * THREADS); ++it) {   // 8 iterations
        const int t = it * THREADS + tid;
        const float4 v0 = pb4[3 * t + 0];
        const float4 v1 = pb4[3 * t + 1];
        const float4 v2 = pb4[3 * t + 2];
        float rz;
        rz = r20 * v0.x + r21 * v0.y + r22 * v0.z; zmin = fminf(zmin, rz); zmax = fmaxf(zmax, rz);
        rz = r20 * v0.w + r21 * v1.x + r22 * v1.y; zmin = fminf(zmin, rz); zmax = fmaxf(zmax, rz);
        rz = r20 * v1.z + r21 * v1.w + r22 * v2.x; zmin = fminf(zmin, rz); zmax = fmaxf(zmax, rz);
        rz = r20 * v2.y + r21 * v2.z + r22 * v2.w; zmin = fminf(zmin, rz); zmax = fmaxf(zmax, rz);
    }
    for (int m = 1; m < 64; m <<= 1) {
        zmin = fminf(zmin, __shfl_xor(zmin, m));
        zmax = fmaxf(zmax, __shfl_xor(zmax, m));
    }
    if ((tid & 63) == 0) { wmin[tid >> 6] = zmin; wmax[tid >> 6] = zmax; }
    __syncthreads();     // publishes wmin/wmax AND the zeroed tile
#pragma unroll
    for (int w = 0; w < NW; ++w) {
        zmin = fminf(zmin, wmin[w]);
        zmax = fmaxf(zmax, wmax[w]);
    }
    const float inv = 0.7f / (zmax - zmin + 1e-6f);

    // ---- pass 2: transform + splat (points L2-hot) ----
    auto splat = [&](float x, float y, float z) {
        const float rx = r00 * x + r02 * z;
        const float ry = r10 * x + r11 * y + r12 * z;
        const float rz = r20 * x + r21 * y + r22 * z;
        const float px = (rx + 1.0f) * (0.5f * IMG) - 0.5f;
        const float py = (ry + 1.0f) * (0.5f * IMG) - 0.5f;
        const float fx = floorf(px);
        const float fy = floorf(py);
        // mask: px1>=0 && py1>=0 && px2<224 && py2<224
        if (fx >= 0.0f && fy >= 0.0f && fx < (float)(IMG - 1) && fy < (float)(IMG - 1)) {
            const float feat = 0.3f + (rz - zmin) * inv;
            const float wx2 = px - fx, wx1 = 1.0f - wx2;
            const float wy2 = py - fy, wy1 = 1.0f - wy2;
            const int ix = (int)fx;
            const int r0 = (int)fy - y0;
            const int r1 = r0 + 1;
            if (r0 >= 0 && r0 < RPB) {
                atomicAdd(&tile[r0 * IMG + ix],     wx1 * wy1 * feat);
                atomicAdd(&tile[r0 * IMG + ix + 1], wx2 * wy1 * feat);
            }
            if (r1 >= 0 && r1 < RPB) {
                atomicAdd(&tile[r1 * IMG + ix],     wx1 * wy2 * feat);
                atomicAdd(&tile[r1 * IMG + ix + 1], wx2 * wy2 * feat);
            }
        }
    };

#pragma unroll
    for (int it = 0; it < NPTS / (4 * THREADS); ++it) {   // 8 iterations
        const int t = it * THREADS + tid;
        const float4 v0 = pb4[3 * t + 0];
        const float4 v1 = pb4[3 * t + 1];
        const float4 v2 = pb4[3 * t + 2];
        splat(v0.x, v0.y, v0.z);
        splat(v0.w, v1.x, v1.y);
        splat(v1.z, v1.w, v2.x);
        splat(v2.y, v2.z, v2.w);
    }

    __syncthreads();

    // ---- writeout: exclusive region -> 3 channels, nontemporal ----
    const vf4* __restrict__ t4 = (const vf4*)tile;
    vf4* __restrict__ o4 = (vf4*)(out + (size_t)b * 3 * HW + (size_t)y0 * IMG);
    for (int i = tid; i < TILEF / 4; i += THREADS) {
        const vf4 v = t4[i];
        __builtin_nontemporal_store(v, o4 + i);
        __builtin_nontemporal_store(v, o4 + i + HW4);
        __builtin_nontemporal_store(v, o4 + i + 2 * HW4);
    }
}

extern "C" void kernel_launch(void* const* d_in, const int* in_sizes, int n_in,
                              void* d_out, int out_size, void* d_ws, size_t ws_size,
                              hipStream_t stream) {
    const float* pts = (const float*)d_in[0];
    const float* az  = (const float*)d_in[1];
    const float* el  = (const float*)d_in[2];
    float* out = (float*)d_out;

    k_render<<<NB * GROUPS, THREADS, 0, stream>>>(pts, az, el, out);
}